// Round 8
// baseline (81.671 us; speedup 1.0000x reference)
//
#include <hip/hip_runtime.h>

// EDeeperGCN: out[e] = relu(cat(x[src],x[dst]) @ W1 + b1) @ W2 + b2
// AB[n] = [x[n]@W1_top + b1 | x[n]@W1_bot]  (f16, in d_ws)
// out[e] = relu(A[src[e]] + B[dst[e]]) @ W2 + b2
//
// Both GEMMs on mfma_f32_16x16x32_f16 with the proven fragment map:
//   lane = 16*g + r;  A: row r, k = 32*st + 8g + j;  B: col r, same k
//   C/D (HW, m89): col = lane&15, row = (lane>>4)*4 + reg
// edge_mlp: 32 edges/wave (2 iters x 16); ALL 16 gathers issued before any
//   compute (launch_bounds(256,4) gives the register budget so the compiler
//   keeps them in flight); gathers line-perfect (4 lanes x 16B = one 64B
//   line per edge per instr). Grid 5000 blocks = 78 waves/CU queued.
// node_AB: 1 tile/block (625 blocks), weights from pre-transposed f16 W1T.

typedef _Float16 f16;
typedef _Float16 f16x8 __attribute__((ext_vector_type(8)));
typedef float    f32x4 __attribute__((ext_vector_type(4)));

#define HID  128
#define TWOH 256
#define OUTD 10

// ---------------- Kernel 0: W1T[c][k] = W1cat[k][c], f16 [256][128] ----------------
__global__ __launch_bounds__(256) void w1_transpose(
    const float* __restrict__ W1,   // [256, 128]
    f16* __restrict__ W1T)          // [256, 128] (c-major)
{
    const int idx = blockIdx.x * 256 + threadIdx.x;   // 32768 elements
    const int c = idx >> 7, k = idx & 127;
    const float v = (c < HID) ? W1[k * HID + c]
                              : W1[(HID + k) * HID + (c - HID)];
    W1T[idx] = (f16)v;                                 // coalesced f16 writes
}

// ---------------- Kernel 1: AB = x @ W1cat + [b1|0], f16 out, MFMA ----------------
__global__ __launch_bounds__(256, 4) void node_AB(
    const float* __restrict__ x,    // [N, 128]
    const f16* __restrict__ W1T,    // [256, 128] c-major
    const float* __restrict__ b1,   // [128]
    f16* __restrict__ AB,           // [N, 256]
    int n_nodes)
{
    const int t = threadIdx.x;
    const int lane = t & 63;
    const int r = lane & 15, g = lane >> 4;
    const int wv = t >> 6;
    const int c0 = wv * 64;
    const int n0 = blockIdx.x * 16;

    // x A-fragments first (HBM latency starts early)
    const int xrow = (n0 + r < n_nodes) ? (n0 + r) : (n_nodes - 1);
    float4 xl[4][2];
#pragma unroll
    for (int st = 0; st < 4; ++st) {
        const float* xp = x + (long)xrow * HID + st * 32 + g * 8;
        xl[st][0] = *(const float4*)xp;
        xl[st][1] = *(const float4*)(xp + 4);
    }

    // B-fragments: one b128 load each (j contiguous in W1T); 16 total.
    f16x8 w1f[4][4];
    float bias[4];
#pragma unroll
    for (int ct = 0; ct < 4; ++ct) {
        const int c = c0 + ct * 16 + r;
        bias[ct] = (c < HID) ? b1[c] : 0.f;
#pragma unroll
        for (int st = 0; st < 4; ++st)
            w1f[ct][st] = *(const f16x8*)(W1T + (long)c * HID + st * 32 + g * 8);
    }

    f32x4 acc[4] = {{0,0,0,0},{0,0,0,0},{0,0,0,0},{0,0,0,0}};
#pragma unroll
    for (int st = 0; st < 4; ++st) {
        f16x8 a;
        a[0] = (f16)xl[st][0].x; a[1] = (f16)xl[st][0].y;
        a[2] = (f16)xl[st][0].z; a[3] = (f16)xl[st][0].w;
        a[4] = (f16)xl[st][1].x; a[5] = (f16)xl[st][1].y;
        a[6] = (f16)xl[st][1].z; a[7] = (f16)xl[st][1].w;
#pragma unroll
        for (int ct = 0; ct < 4; ++ct)
            acc[ct] = __builtin_amdgcn_mfma_f32_16x16x32_f16(a, w1f[ct][st], acc[ct], 0, 0, 0);
    }

#pragma unroll
    for (int ct = 0; ct < 4; ++ct) {
        const int c = c0 + ct * 16 + r;
#pragma unroll
        for (int q = 0; q < 4; ++q) {
            const int node = n0 + g * 4 + q;          // D row = node-within-tile
            if (node < n_nodes)
                AB[(long)node * TWOH + c] = (f16)(acc[ct][q] + bias[ct]);
        }
    }
}

// ---------------- Kernel 2: edge gather + relu + [128x10] GEMM, MFMA ----------------
// Block = 4 waves x 32 edges = 128 edges. All gathers issued before compute.
__global__ __launch_bounds__(256, 4) void edge_mlp(
    const f16* __restrict__ AB,     // [N, 256] = 32 f16x8 chunks per row
    const int* __restrict__ ei,     // [2, E]
    const float* __restrict__ W2,   // [128, 10]
    const float* __restrict__ b2,   // [10]
    float* __restrict__ out,        // [E, 10]
    int n_edges)
{
    const int t = threadIdx.x;
    const int lane = t & 63;
    const int r = lane & 15, g = lane >> 4;
    const int wv = t >> 6;

    // W2 B-fragment in 16 VGPRs: col r (zeros for r>=10); k = 32*st + 8g + j
    const bool cok = (r < OUTD);
    const int cw = cok ? r : 0;
    f16x8 w2f[4];
#pragma unroll
    for (int st = 0; st < 4; ++st) {
        f16x8 v;
#pragma unroll
        for (int j = 0; j < 8; ++j) {
            const float w = W2[(long)(st * 32 + g * 8 + j) * OUTD + cw];
            v[j] = cok ? (f16)w : (f16)0.f;
        }
        w2f[st] = v;
    }
    const float bj = cok ? b2[r] : 0.f;

    const f16x8* __restrict__ ABv = (const f16x8*)AB;
    const long eb = (long)blockIdx.x * 128 + wv * 32;

    // both iterations' indices (16 consecutive dwords per load -> 1 line)
    const long e0 = eb + r, e1 = eb + 16 + r;
    const long c0i = (e0 < n_edges) ? e0 : (n_edges - 1);
    const long c1i = (e1 < n_edges) ? e1 : (n_edges - 1);
    const int sn0 = ei[c0i], dn0 = ei[(long)n_edges + c0i];
    const int sn1 = ei[c1i], dn1 = ei[(long)n_edges + c1i];

    // ALL 16 gathers up front; counted waitcnt lets compute start after
    // the first 8 while iter-1's loads are still in flight.
    const long a0 = (long)sn0 * 32, b0 = (long)dn0 * 32;
    const long a1 = (long)sn1 * 32, b1 = (long)dn1 * 32;
    f16x8 pa0[4], pc0[4], pa1[4], pc1[4];
#pragma unroll
    for (int st = 0; st < 4; ++st) {
        pa0[st] = ABv[a0 + st * 4 + g];
        pc0[st] = ABv[b0 + 16 + st * 4 + g];
    }
#pragma unroll
    for (int st = 0; st < 4; ++st) {
        pa1[st] = ABv[a1 + st * 4 + g];
        pc1[st] = ABv[b1 + 16 + st * 4 + g];
    }

    const f16x8 z = {0, 0, 0, 0, 0, 0, 0, 0};

    f32x4 acc0 = {0, 0, 0, 0};
#pragma unroll
    for (int st = 0; st < 4; ++st) {
        const f16x8 s = __builtin_elementwise_max(pa0[st] + pc0[st], z);
        acc0 = __builtin_amdgcn_mfma_f32_16x16x32_f16(s, w2f[st], acc0, 0, 0, 0);
    }
    if (cok) {
#pragma unroll
        for (int q = 0; q < 4; ++q) {
            const long ee = eb + g * 4 + q;           // D row = edge-within-tile
            if (ee < n_edges) out[ee * OUTD + r] = acc0[q] + bj;
        }
    }

    f32x4 acc1 = {0, 0, 0, 0};
#pragma unroll
    for (int st = 0; st < 4; ++st) {
        const f16x8 s = __builtin_elementwise_max(pa1[st] + pc1[st], z);
        acc1 = __builtin_amdgcn_mfma_f32_16x16x32_f16(s, w2f[st], acc1, 0, 0, 0);
    }
    if (cok) {
#pragma unroll
        for (int q = 0; q < 4; ++q) {
            const long ee = eb + 16 + g * 4 + q;
            if (ee < n_edges) out[ee * OUTD + r] = acc1[q] + bj;
        }
    }
}

extern "C" void kernel_launch(void* const* d_in, const int* in_sizes, int n_in,
                              void* d_out, int out_size, void* d_ws, size_t ws_size,
                              hipStream_t stream) {
    const float* x  = (const float*)d_in[0];
    const int*   ei = (const int*)d_in[1];
    const float* W1 = (const float*)d_in[2];
    const float* b1 = (const float*)d_in[3];
    const float* W2 = (const float*)d_in[4];
    const float* b2 = (const float*)d_in[5];
    float* out = (float*)d_out;

    const int n_nodes = in_sizes[0] / HID;          // 10000
    const int n_edges = in_sizes[1] / 2;            // 640000

    f16* AB  = (f16*)d_ws;                          // [n_nodes, 256] f16 = 5.12 MB
    f16* W1T = AB + (long)n_nodes * TWOH;           // 64 KB, 16B-aligned

    w1_transpose<<<(TWOH * HID) / 256, 256, 0, stream>>>(W1, W1T);

    node_AB<<<(n_nodes + 15) / 16, 256, 0, stream>>>(x, W1T, b1, AB, n_nodes);

    edge_mlp<<<(n_edges + 127) / 128, 256, 0, stream>>>(AB, ei, W2, b2, out, n_edges);
}

// Round 9
// 61.782 us; speedup vs baseline: 1.3219x; 1.3219x over previous
//
#include <hip/hip_runtime.h>

// EDeeperGCN: out[e] = relu(cat(x[src],x[dst]) @ W1 + b1) @ W2 + b2
// AB[n] = [x[n]@W1_top + b1 | x[n]@W1_bot]  (f16, in d_ws)
// out[e] = relu(A[src[e]] + B[dst[e]]) @ W2 + b2
//
// Both GEMMs on mfma_f32_16x16x32_f16, proven fragment map:
//   lane = 16*g + r;  A: row r, k = 32*st + 8g + j;  B: col r, same k
//   C/D (HW, m89): col = lane&15, row = (lane>>4)*4 + reg
// prep_weights packs per-lane B-fragments (W1P, W2P) so kernel prologues are
// coalesced b128 loads with zero converts (round-8 regression was this).
// edge_mlp: 128 edges/wave, depth-3 gather ring pinned by sched_barrier(0)
// so ~24 line-perfect gathers stay in flight per wave.

typedef _Float16 f16;
typedef _Float16 f16x8 __attribute__((ext_vector_type(8)));
typedef float    f32x4 __attribute__((ext_vector_type(4)));

#define HID  128
#define TWOH 256
#define OUTD 10

// ---------------- Kernel 0: pack weight fragments ----------------
// W1P slot = (wv*16 + ct*4 + st)*64 + lane : j -> W1cat[32st+8g+j][64wv+16ct+r]
// W2P slot = st*64 + lane                  : j -> W2[32st+8g+j][r] (0 if r>=10)
__global__ __launch_bounds__(256) void prep_weights(
    const float* __restrict__ W1,   // [256, 128]
    const float* __restrict__ W2,   // [128, 10]
    f16* __restrict__ W1P,          // 4096 slots x 8
    f16* __restrict__ W2P)          // 256 slots x 8
{
    const int slot = blockIdx.x * 256 + threadIdx.x;
    if (slot < 4096) {
        const int lane = slot & 63, i = slot >> 6;
        const int r = lane & 15, g = lane >> 4;
        const int wv = i >> 4, ct = (i >> 2) & 3, st = i & 3;
        const int c = wv * 64 + ct * 16 + r;
        f16x8 v;
#pragma unroll
        for (int j = 0; j < 8; ++j) {
            const int k = st * 32 + g * 8 + j;
            const float w = (c < HID) ? W1[k * HID + c]
                                      : W1[(HID + k) * HID + (c - HID)];
            v[j] = (f16)w;
        }
        *(f16x8*)(W1P + (long)slot * 8) = v;
    } else if (slot < 4096 + 256) {
        const int s2 = slot - 4096;
        const int lane = s2 & 63, st = s2 >> 6;
        const int r = lane & 15, g = lane >> 4;
        f16x8 v;
#pragma unroll
        for (int j = 0; j < 8; ++j)
            v[j] = (r < OUTD) ? (f16)W2[(st * 32 + g * 8 + j) * OUTD + r] : (f16)0.f;
        *(f16x8*)(W2P + (long)s2 * 8) = v;
    }
}

// ---------------- Kernel 1: AB = x @ W1cat + [b1|0], f16 out, MFMA ----------------
__global__ __launch_bounds__(256, 3) void node_AB(
    const float* __restrict__ x,    // [N, 128]
    const f16* __restrict__ W1P,    // packed fragments
    const float* __restrict__ b1,   // [128]
    f16* __restrict__ AB,           // [N, 256]
    int n_nodes)
{
    const int t = threadIdx.x;
    const int lane = t & 63;
    const int r = lane & 15, g = lane >> 4;
    const int wv = t >> 6;
    const int n0 = blockIdx.x * 16;

    // x A-fragments first (HBM latency starts early)
    const int xrow = (n0 + r < n_nodes) ? (n0 + r) : (n_nodes - 1);
    float4 xl[4][2];
#pragma unroll
    for (int st = 0; st < 4; ++st) {
        const float* xp = x + (long)xrow * HID + st * 32 + g * 8;
        xl[st][0] = *(const float4*)xp;
        xl[st][1] = *(const float4*)(xp + 4);
    }

    // B-fragments: 16 coalesced b128 loads (1 KB/instr across the wave)
    f16x8 w1f[4][4];
    float bias[4];
#pragma unroll
    for (int ct = 0; ct < 4; ++ct) {
        const int c = wv * 64 + ct * 16 + r;
        bias[ct] = (c < HID) ? b1[c] : 0.f;
#pragma unroll
        for (int st = 0; st < 4; ++st)
            w1f[ct][st] = *(const f16x8*)(W1P + ((long)((wv * 16 + ct * 4 + st)) * 64 + lane) * 8);
    }

    f32x4 acc[4] = {{0,0,0,0},{0,0,0,0},{0,0,0,0},{0,0,0,0}};
#pragma unroll
    for (int st = 0; st < 4; ++st) {
        f16x8 a;
        a[0] = (f16)xl[st][0].x; a[1] = (f16)xl[st][0].y;
        a[2] = (f16)xl[st][0].z; a[3] = (f16)xl[st][0].w;
        a[4] = (f16)xl[st][1].x; a[5] = (f16)xl[st][1].y;
        a[6] = (f16)xl[st][1].z; a[7] = (f16)xl[st][1].w;
#pragma unroll
        for (int ct = 0; ct < 4; ++ct)
            acc[ct] = __builtin_amdgcn_mfma_f32_16x16x32_f16(a, w1f[ct][st], acc[ct], 0, 0, 0);
    }

#pragma unroll
    for (int ct = 0; ct < 4; ++ct) {
        const int c = wv * 64 + ct * 16 + r;
#pragma unroll
        for (int q = 0; q < 4; ++q) {
            const int node = n0 + g * 4 + q;          // D row = node-within-tile
            if (node < n_nodes)
                AB[(long)node * TWOH + c] = (f16)(acc[ct][q] + bias[ct]);
        }
    }
}

// ---------------- Kernel 2: edge gather + relu + [128x10] GEMM, MFMA ----------------
// Block = 4 waves x 128 edges = 512 edges. Depth-3 pinned gather ring.
__global__ __launch_bounds__(256, 3) void edge_mlp(
    const f16* __restrict__ AB,     // [N, 256] = 32 f16x8 chunks per row
    const int* __restrict__ ei,     // [2, E]
    const f16* __restrict__ W2P,    // packed fragments
    const float* __restrict__ b2,   // [10]
    float* __restrict__ out,        // [E, 10]
    int n_edges)
{
    const int t = threadIdx.x;
    const int lane = t & 63;
    const int r = lane & 15, g = lane >> 4;
    const int wv = t >> 6;

    // W2 B-fragment: 4 coalesced b128 loads, zero converts
    f16x8 w2f[4];
#pragma unroll
    for (int st = 0; st < 4; ++st)
        w2f[st] = *(const f16x8*)(W2P + ((long)st * 64 + lane) * 8);
    const int rc = (r < OUTD) ? r : 0;
    const float bj = b2[rc];

    const f16x8* __restrict__ ABv = (const f16x8*)AB;
    const long eb = (long)blockIdx.x * 512 + wv * 128;

    // all 8 iterations' indices up front (1 line per load instr)
    int sn[8], dn[8];
#pragma unroll
    for (int it = 0; it < 8; ++it) {
        const long e = eb + it * 16 + r;
        const long ec = (e < n_edges) ? e : (n_edges - 1);
        sn[it] = ei[ec];
        dn[it] = ei[(long)n_edges + ec];
    }

    const f16x8 zt = {0, 0, 0, 0, 0, 0, 0, 0};

#define GATHER(Pa, Pc, IT)                                                  \
    f16x8 Pa[4], Pc[4];                                                     \
    {                                                                       \
        const long ab_ = (long)sn[IT] * 32, bb_ = (long)dn[IT] * 32;        \
        _Pragma("unroll")                                                   \
        for (int st = 0; st < 4; ++st) {                                    \
            Pa[st] = ABv[ab_ + st * 4 + g];                                 \
            Pc[st] = ABv[bb_ + 16 + st * 4 + g];                            \
        }                                                                   \
    }

#define COMPSTORE(Pa, Pc, IT)                                               \
    {                                                                       \
        f32x4 acc = {0, 0, 0, 0};                                           \
        _Pragma("unroll")                                                   \
        for (int st = 0; st < 4; ++st) {                                    \
            const f16x8 s = __builtin_elementwise_max(Pa[st] + Pc[st], zt); \
            acc = __builtin_amdgcn_mfma_f32_16x16x32_f16(s, w2f[st], acc, 0, 0, 0); \
        }                                                                   \
        if (r < OUTD) {                                                     \
            _Pragma("unroll")                                               \
            for (int q = 0; q < 4; ++q) {                                   \
                const long ee = eb + IT * 16 + g * 4 + q;                   \
                if (ee < n_edges) out[ee * OUTD + r] = acc[q] + bj;         \
            }                                                               \
        }                                                                   \
    }

    GATHER(a0, c0, 0)
    GATHER(a1, c1, 1)
    GATHER(a2, c2, 2)
    __builtin_amdgcn_sched_barrier(0);
    COMPSTORE(a0, c0, 0)
    GATHER(a3, c3, 3)
    __builtin_amdgcn_sched_barrier(0);
    COMPSTORE(a1, c1, 1)
    GATHER(a4, c4, 4)
    __builtin_amdgcn_sched_barrier(0);
    COMPSTORE(a2, c2, 2)
    GATHER(a5, c5, 5)
    __builtin_amdgcn_sched_barrier(0);
    COMPSTORE(a3, c3, 3)
    GATHER(a6, c6, 6)
    __builtin_amdgcn_sched_barrier(0);
    COMPSTORE(a4, c4, 4)
    GATHER(a7, c7, 7)
    __builtin_amdgcn_sched_barrier(0);
    COMPSTORE(a5, c5, 5)
    COMPSTORE(a6, c6, 6)
    COMPSTORE(a7, c7, 7)

#undef GATHER
#undef COMPSTORE
}

extern "C" void kernel_launch(void* const* d_in, const int* in_sizes, int n_in,
                              void* d_out, int out_size, void* d_ws, size_t ws_size,
                              hipStream_t stream) {
    const float* x  = (const float*)d_in[0];
    const int*   ei = (const int*)d_in[1];
    const float* W1 = (const float*)d_in[2];
    const float* b1 = (const float*)d_in[3];
    const float* W2 = (const float*)d_in[4];
    const float* b2 = (const float*)d_in[5];
    float* out = (float*)d_out;

    const int n_nodes = in_sizes[0] / HID;          // 10000
    const int n_edges = in_sizes[1] / 2;            // 640000

    f16* AB  = (f16*)d_ws;                          // [n_nodes, 256] f16 = 5.12 MB
    f16* W1P = AB + (long)n_nodes * TWOH;           // 64 KB
    f16* W2P = W1P + 4096 * 8;                      // 4 KB

    prep_weights<<<17, 256, 0, stream>>>(W1, W2, W1P, W2P);

    node_AB<<<(n_nodes + 15) / 16, 256, 0, stream>>>(x, W1P, b1, AB, n_nodes);

    edge_mlp<<<(n_edges + 511) / 512, 256, 0, stream>>>(AB, ei, W2P, b2, out, n_edges);
}

// Round 11
// 60.351 us; speedup vs baseline: 1.3533x; 1.0237x over previous
//
#include <hip/hip_runtime.h>

// EDeeperGCN: out[e] = relu(cat(x[src],x[dst]) @ W1 + b1) @ W2 + b2
// AB[n] = [x[n]@W1_top + b1 | x[n]@W1_bot]  (f16, in d_ws)
// out[e] = relu(A[src[e]] + B[dst[e]]) @ W2 + b2
//
// Both GEMMs on mfma_f32_16x16x32_f16, proven fragment map:
//   lane = 16*g + r;  A: row r, k = 32*st + 8g + j;  B: col r, same k
//   C/D (HW, m89): col = lane&15, row = (lane>>4)*4 + reg
// edge_mlp inner loop is INLINE ASM: depth-3 gather ring with hand-counted
// s_waitcnt vmcnt(N) (never 0 mid-loop) -- the compiler provably collapses
// source-level pipelines here (r7/r8/r9: VGPR_Count 64/36/72).
// r10 fix: asm operands must be ext_vector_type, not HIP float4 structs.

typedef _Float16 f16;
typedef _Float16 f16x8 __attribute__((ext_vector_type(8)));
typedef float    f32x4 __attribute__((ext_vector_type(4)));

#define HID  128
#define TWOH 256
#define OUTD 10

// ---------------- Kernel 0: pack weight fragments ----------------
__global__ __launch_bounds__(256) void prep_weights(
    const float* __restrict__ W1,   // [256, 128]
    const float* __restrict__ W2,   // [128, 10]
    f16* __restrict__ W1P,          // 4096 slots x 8
    f16* __restrict__ W2P)          // 256 slots x 8
{
    const int slot = blockIdx.x * 256 + threadIdx.x;
    if (slot < 4096) {
        const int lane = slot & 63, i = slot >> 6;
        const int r = lane & 15, g = lane >> 4;
        const int wv = i >> 4, ct = (i >> 2) & 3, st = i & 3;
        const int c = wv * 64 + ct * 16 + r;
        f16x8 v;
#pragma unroll
        for (int j = 0; j < 8; ++j) {
            const int k = st * 32 + g * 8 + j;
            const float w = (c < HID) ? W1[k * HID + c]
                                      : W1[(HID + k) * HID + (c - HID)];
            v[j] = (f16)w;
        }
        *(f16x8*)(W1P + (long)slot * 8) = v;
    } else if (slot < 4096 + 256) {
        const int s2 = slot - 4096;
        const int lane = s2 & 63, st = s2 >> 6;
        const int r = lane & 15, g = lane >> 4;
        f16x8 v;
#pragma unroll
        for (int j = 0; j < 8; ++j)
            v[j] = (r < OUTD) ? (f16)W2[(st * 32 + g * 8 + j) * OUTD + r] : (f16)0.f;
        *(f16x8*)(W2P + (long)s2 * 8) = v;
    }
}

// ---------------- Kernel 1: AB = x @ W1cat + [b1|0], f16 out, MFMA ----------------
__global__ __launch_bounds__(256, 3) void node_AB(
    const float* __restrict__ x,    // [N, 128]
    const f16* __restrict__ W1P,    // packed fragments
    const float* __restrict__ b1,   // [128]
    f16* __restrict__ AB,           // [N, 256]
    int n_nodes)
{
    const int t = threadIdx.x;
    const int lane = t & 63;
    const int r = lane & 15, g = lane >> 4;
    const int wv = t >> 6;
    const int n0 = blockIdx.x * 16;

    const int xrow = (n0 + r < n_nodes) ? (n0 + r) : (n_nodes - 1);
    float4 xl[4][2];
#pragma unroll
    for (int st = 0; st < 4; ++st) {
        const float* xp = x + (long)xrow * HID + st * 32 + g * 8;
        xl[st][0] = *(const float4*)xp;
        xl[st][1] = *(const float4*)(xp + 4);
    }

    f16x8 w1f[4][4];
    float bias[4];
#pragma unroll
    for (int ct = 0; ct < 4; ++ct) {
        const int c = wv * 64 + ct * 16 + r;
        bias[ct] = (c < HID) ? b1[c] : 0.f;
#pragma unroll
        for (int st = 0; st < 4; ++st)
            w1f[ct][st] = *(const f16x8*)(W1P + ((long)((wv * 16 + ct * 4 + st)) * 64 + lane) * 8);
    }

    f32x4 acc[4] = {{0,0,0,0},{0,0,0,0},{0,0,0,0},{0,0,0,0}};
#pragma unroll
    for (int st = 0; st < 4; ++st) {
        f16x8 a;
        a[0] = (f16)xl[st][0].x; a[1] = (f16)xl[st][0].y;
        a[2] = (f16)xl[st][0].z; a[3] = (f16)xl[st][0].w;
        a[4] = (f16)xl[st][1].x; a[5] = (f16)xl[st][1].y;
        a[6] = (f16)xl[st][1].z; a[7] = (f16)xl[st][1].w;
#pragma unroll
        for (int ct = 0; ct < 4; ++ct)
            acc[ct] = __builtin_amdgcn_mfma_f32_16x16x32_f16(a, w1f[ct][st], acc[ct], 0, 0, 0);
    }

#pragma unroll
    for (int ct = 0; ct < 4; ++ct) {
        const int c = wv * 64 + ct * 16 + r;
#pragma unroll
        for (int q = 0; q < 4; ++q) {
            const int node = n0 + g * 4 + q;
            if (node < n_nodes)
                AB[(long)node * TWOH + c] = (f16)(acc[ct][q] + bias[ct]);
        }
    }
}

// ---------------- Kernel 2: edge gather + relu + [128x10] GEMM, MFMA ----------------
// Block = 4 waves x 128 edges = 512 edges. Inline-asm depth-3 gather ring.
__global__ __launch_bounds__(256, 3) void edge_mlp(
    const f16* __restrict__ AB,     // [N, 256]
    const int* __restrict__ ei,     // [2, E]
    const f16* __restrict__ W2P,    // packed fragments
    const float* __restrict__ b2,   // [10]
    float* __restrict__ out,        // [E, 10]
    int n_edges)
{
    __shared__ float stage[4][160];                 // 640B per wave
    const int t = threadIdx.x;
    const int lane = t & 63;
    const int r = lane & 15, g = lane >> 4;
    const int wv = t >> 6;

    f16x8 w2f[4];
#pragma unroll
    for (int st = 0; st < 4; ++st)
        w2f[st] = *(const f16x8*)(W2P + ((long)st * 64 + lane) * 8);
    const float bj = b2[(r < OUTD) ? r : 0];

    const long eb = (long)blockIdx.x * 512 + wv * 128;

    int sn[8], dn[8];
#pragma unroll
    for (int it = 0; it < 8; ++it) {
        const long e = eb + it * 16 + r;
        const long ec = (e < n_edges) ? e : (n_edges - 1);
        sn[it] = ei[ec];
        dn[it] = ei[(long)n_edges + ec];
    }

    const f16x8 zt = {0, 0, 0, 0, 0, 0, 0, 0};

    if (eb + 128 <= n_edges) {
        // Force-resolve ALL compiler-issued vmem loads now, so the compiler
        // never inserts its own vmcnt() inside the hand-counted ring.
        asm volatile("" ::
            "v"(w2f[0]), "v"(w2f[1]), "v"(w2f[2]), "v"(w2f[3]), "v"(bj),
            "v"(sn[0]), "v"(sn[1]), "v"(sn[2]), "v"(sn[3]),
            "v"(sn[4]), "v"(sn[5]), "v"(sn[6]), "v"(sn[7]),
            "v"(dn[0]), "v"(dn[1]), "v"(dn[2]), "v"(dn[3]),
            "v"(dn[4]), "v"(dn[5]), "v"(dn[6]), "v"(dn[7]));

#define DECL(IT) f16x8 pa##IT##0, pa##IT##1, pa##IT##2, pa##IT##3, \
                       pc##IT##0, pc##IT##1, pc##IT##2, pc##IT##3;
        DECL(0) DECL(1) DECL(2) DECL(3) DECL(4) DECL(5) DECL(6) DECL(7)

// 8 line-perfect gathers: 2 base addrs + offset:64*st immediates.
#define ISSUE(IT) { \
    const f16* _pa = AB + ((long)sn[IT] * TWOH + g * 8); \
    const f16* _pb = AB + ((long)dn[IT] * TWOH + HID + g * 8); \
    asm volatile("global_load_dwordx4 %0, %1, off"            : "=v"(pa##IT##0) : "v"(_pa)); \
    asm volatile("global_load_dwordx4 %0, %1, off offset:64"  : "=v"(pa##IT##1) : "v"(_pa)); \
    asm volatile("global_load_dwordx4 %0, %1, off offset:128" : "=v"(pa##IT##2) : "v"(_pa)); \
    asm volatile("global_load_dwordx4 %0, %1, off offset:192" : "=v"(pa##IT##3) : "v"(_pa)); \
    asm volatile("global_load_dwordx4 %0, %1, off"            : "=v"(pc##IT##0) : "v"(_pb)); \
    asm volatile("global_load_dwordx4 %0, %1, off offset:64"  : "=v"(pc##IT##1) : "v"(_pb)); \
    asm volatile("global_load_dwordx4 %0, %1, off offset:128" : "=v"(pc##IT##2) : "v"(_pb)); \
    asm volatile("global_load_dwordx4 %0, %1, off offset:192" : "=v"(pc##IT##3) : "v"(_pb)); \
}

// Hand-counted wait, tied to the buffers it guards (defs before, uses after).
#define WAITN(IT, NSTR) \
    asm volatile("s_waitcnt vmcnt(" NSTR ")" \
        : "+v"(pa##IT##0), "+v"(pa##IT##1), "+v"(pa##IT##2), "+v"(pa##IT##3), \
          "+v"(pc##IT##0), "+v"(pc##IT##1), "+v"(pc##IT##2), "+v"(pc##IT##3)); \
    __builtin_amdgcn_sched_barrier(0);

#define COMPUTE(IT) { \
    f32x4 acc = {0, 0, 0, 0}; \
    f16x8 s; \
    s = __builtin_elementwise_max(pa##IT##0 + pc##IT##0, zt); \
    acc = __builtin_amdgcn_mfma_f32_16x16x32_f16(s, w2f[0], acc, 0, 0, 0); \
    s = __builtin_elementwise_max(pa##IT##1 + pc##IT##1, zt); \
    acc = __builtin_amdgcn_mfma_f32_16x16x32_f16(s, w2f[1], acc, 0, 0, 0); \
    s = __builtin_elementwise_max(pa##IT##2 + pc##IT##2, zt); \
    acc = __builtin_amdgcn_mfma_f32_16x16x32_f16(s, w2f[2], acc, 0, 0, 0); \
    s = __builtin_elementwise_max(pa##IT##3 + pc##IT##3, zt); \
    acc = __builtin_amdgcn_mfma_f32_16x16x32_f16(s, w2f[3], acc, 0, 0, 0); \
    if (r < OUTD) { \
        _Pragma("unroll") \
        for (int q = 0; q < 4; ++q) \
            stage[wv][(g * 4 + q) * OUTD + r] = acc[q] + bj; \
    } \
    __builtin_amdgcn_wave_barrier(); \
    if (lane < 40) { \
        const f32x4 vv = *(const f32x4*)&stage[wv][lane * 4]; \
        float* po = out + (eb + IT * 16) * OUTD + lane * 4; \
        asm volatile("global_store_dwordx4 %0, %1, off" :: "v"(po), "v"(vv) : "memory"); \
    } \
    __builtin_amdgcn_wave_barrier(); \
}

        ISSUE(0) ISSUE(1) ISSUE(2)
        WAITN(0, "16") COMPUTE(0) ISSUE(3)
        WAITN(1, "17") COMPUTE(1) ISSUE(4)
        WAITN(2, "18") COMPUTE(2) ISSUE(5)
        WAITN(3, "18") COMPUTE(3) ISSUE(6)
        WAITN(4, "18") COMPUTE(4) ISSUE(7)
        WAITN(5, "18") COMPUTE(5)
        WAITN(6, "10") COMPUTE(6)
        WAITN(7, "2")  COMPUTE(7)
        asm volatile("s_waitcnt vmcnt(0)");
#undef DECL
#undef ISSUE
#undef WAITN
#undef COMPUTE
    } else {
        // generic tail path (unused at E = 640000)
#pragma unroll
        for (int it = 0; it < 8; ++it) {
            f32x4 acc = {0, 0, 0, 0};
#pragma unroll
            for (int st = 0; st < 4; ++st) {
                const f16x8 a = *(const f16x8*)(AB + ((long)sn[it] * TWOH + st * 32 + g * 8));
                const f16x8 c = *(const f16x8*)(AB + ((long)dn[it] * TWOH + HID + st * 32 + g * 8));
                const f16x8 s = __builtin_elementwise_max(a + c, zt);
                acc = __builtin_amdgcn_mfma_f32_16x16x32_f16(s, w2f[st], acc, 0, 0, 0);
            }
            if (r < OUTD) {
#pragma unroll
                for (int q = 0; q < 4; ++q) {
                    const long ee = eb + it * 16 + g * 4 + q;
                    if (ee < n_edges) out[ee * OUTD + r] = acc[q] + bj;
                }
            }
        }
    }
}

extern "C" void kernel_launch(void* const* d_in, const int* in_sizes, int n_in,
                              void* d_out, int out_size, void* d_ws, size_t ws_size,
                              hipStream_t stream) {
    const float* x  = (const float*)d_in[0];
    const int*   ei = (const int*)d_in[1];
    const float* W1 = (const float*)d_in[2];
    const float* b1 = (const float*)d_in[3];
    const float* W2 = (const float*)d_in[4];
    const float* b2 = (const float*)d_in[5];
    float* out = (float*)d_out;

    const int n_nodes = in_sizes[0] / HID;          // 10000
    const int n_edges = in_sizes[1] / 2;            // 640000

    f16* AB  = (f16*)d_ws;                          // [n_nodes, 256] f16 = 5.12 MB
    f16* W1P = AB + (long)n_nodes * TWOH;           // 64 KB
    f16* W2P = W1P + 4096 * 8;                      // 4 KB

    prep_weights<<<17, 256, 0, stream>>>(W1, W2, W1P, W2P);

    node_AB<<<(n_nodes + 15) / 16, 256, 0, stream>>>(x, W1P, b1, AB, n_nodes);

    edge_mlp<<<(n_edges + 511) / 512, 256, 0, stream>>>(AB, ei, W2P, b2, out, n_edges);
}